// Round 18
// baseline (232.061 us; speedup 1.0000x reference)
//
#include <hip/hip_runtime.h>
#include <math.h>

#define NN 100000
#define E0 1600000
#define ETOT (E0 + NN)
#define NEG 0.2f

#define NB 512          // dst buckets
#define BS 196          // nodes per bucket (NB*BS >= NN)
#define CHUNK 4096      // edges per k_bin block
#define PPT 16          // pairs per thread
#define MAXP 4096       // max pairs per bucket (mean 3136, sigma 56)

typedef __attribute__((ext_vector_type(2))) float f32x2;

// ---- packed-fp32 VOP3P helpers (verified assembling on gfx950 in R10) ------
__device__ __forceinline__ f32x2 pk_fma(f32x2 a, f32x2 b, f32x2 c) {
    f32x2 d;
    asm("v_pk_fma_f32 %0, %1, %2, %3" : "=v"(d) : "v"(a), "v"(b), "v"(c));
    return d;
}
// broadcast src0.lo to both lanes
__device__ __forceinline__ f32x2 pk_fma_blo(f32x2 a, f32x2 b, f32x2 c) {
    f32x2 d;
    asm("v_pk_fma_f32 %0, %1, %2, %3 op_sel:[0,0,0] op_sel_hi:[0,1,1]"
        : "=v"(d) : "v"(a), "v"(b), "v"(c));
    return d;
}
// broadcast src0.hi to both lanes
__device__ __forceinline__ f32x2 pk_fma_bhi(f32x2 a, f32x2 b, f32x2 c) {
    f32x2 d;
    asm("v_pk_fma_f32 %0, %1, %2, %3 op_sel:[1,0,0] op_sel_hi:[1,1,1]"
        : "=v"(d) : "v"(a), "v"(b), "v"(c));
    return d;
}
__device__ __forceinline__ f32x2 pk_mul(f32x2 a, f32x2 b) {
    f32x2 d;
    asm("v_pk_mul_f32 %0, %1, %2" : "=v"(d) : "v"(a), "v"(b));
    return d;
}

// ---- DPP cross-lane adds (VALU pipe, no LDS latency) -----------------------
template <int CTRL>
__device__ __forceinline__ float dppadd(float v) {
    int t = __builtin_amdgcn_update_dpp(0, __float_as_int(v), CTRL, 0xf, 0xf, true);
    return v + __int_as_float(t);
}
// full 64-lane sum, every lane gets the result
__device__ __forceinline__ float wsum64(float v) {
    v = dppadd<0xB1>(v);
    v = dppadd<0x4E>(v);
    v = dppadd<0x141>(v);
    v = dppadd<0x140>(v);
    v += __shfl_xor(v, 16);
    v += __shfl_xor(v, 32);
    return v;
}
__device__ __forceinline__ unsigned f2bf_rn(float f) {
    unsigned u = __float_as_uint(f);
    return (u + 0x7FFFu + ((u >> 16) & 1u)) >> 16;
}

// ---- pass A: bucket histogram (LDS-aggregated) + fused xr1 = x @ W1r -------
__global__ void k_bhist(const int* __restrict__ ei, int* __restrict__ bcnt,
                        const float* __restrict__ x, const float* __restrict__ Wr,
                        float* __restrict__ xr1) {
    __shared__ int h[NB];
    int tid = threadIdx.x;
    for (int i = tid; i < NB; i += 256) h[i] = 0;
    __syncthreads();
    int stride = gridDim.x * 256;
    for (int e = blockIdx.x * 256 + tid; e < E0; e += stride)
        atomicAdd(&h[ei[E0 + e] / BS], 1);
    __syncthreads();
    for (int i = tid; i < NB; i += 256)
        if (h[i]) atomicAdd(&bcnt[i], h[i]);
    // fused, independent: xr1 (no sync needed; different outputs)
    for (int t = blockIdx.x * 256 + tid; t < NN * 16; t += stride) {
        int n = t >> 4;
        int j = (t & 15) << 2;
        const float4 xv = *(const float4*)(x + (long long)n * 4);
        float4 a = {0.f, 0.f, 0.f, 0.f};
#pragma unroll
        for (int k = 0; k < 4; ++k) {
            float4 w = *(const float4*)(Wr + k * 64 + j);
            float xk = k == 0 ? xv.x : k == 1 ? xv.y : k == 2 ? xv.z : xv.w;
            a.x += xk * w.x; a.y += xk * w.y;
            a.z += xk * w.z; a.w += xk * w.w;
        }
        *(float4*)(xr1 + (long long)n * 64 + j) = a;
    }
}

// ---- pass B: scan bucket counts --------------------------------------------
__global__ void k_bscan(const int* __restrict__ bcnt, int* __restrict__ boff,
                        int* __restrict__ srcsBase, int* __restrict__ cursor,
                        int* __restrict__ rs) {
    __shared__ int s[NB];
    int tid = threadIdx.x;
    int v = bcnt[tid];
    s[tid] = v;
    __syncthreads();
    for (int off = 1; off < NB; off <<= 1) {
        int t = (tid >= off) ? s[tid - off] : 0;
        __syncthreads();
        s[tid] += t;
        __syncthreads();
    }
    int excl = s[tid] - v;
    boff[tid] = excl;
    cursor[tid] = excl;
    int n0 = tid * BS;
    if (n0 > NN) n0 = NN;
    srcsBase[tid] = excl + n0;  // + self-loops of all earlier nodes
    if (tid == 0) rs[NN] = ETOT;  // sentinel
}

// ---- pass C: bin edges into bucket-sorted pair array (run-aggregated) ------
__global__ void k_bin(const int* __restrict__ ei, int* __restrict__ cursor,
                      int2* __restrict__ binned) {
    __shared__ int hist[NB];
    __shared__ int basesh[NB];
    int tid = threadIdx.x;
    long long cbase = (long long)blockIdx.x * CHUNK;
    for (int i = tid; i < NB; i += 256) hist[i] = 0;
    __syncthreads();
    int srcv[PPT], dstv[PPT], rank[PPT], bkt[PPT];
#pragma unroll
    for (int k = 0; k < PPT; ++k) {
        long long e = cbase + k * 256 + tid;
        if (e < E0) {
            int s_ = ei[e];
            int d_ = ei[E0 + e];
            int b = d_ / BS;
            rank[k] = atomicAdd(&hist[b], 1);
            srcv[k] = s_;
            dstv[k] = d_;
            bkt[k] = b;
        } else {
            bkt[k] = -1;
        }
    }
    __syncthreads();
    for (int i = tid; i < NB; i += 256)
        if (hist[i] > 0) basesh[i] = atomicAdd(&cursor[i], hist[i]);
    __syncthreads();
#pragma unroll
    for (int k = 0; k < PPT; ++k)
        if (bkt[k] >= 0) {
            int2 p;
            p.x = srcv[k];
            p.y = dstv[k];
            binned[basesh[bkt[k]] + rank[k]] = p;
        }
}

// ---- pass D: per-bucket finalize: row_start + dst-sorted srcs (coalesced) --
__global__ void k_bfin(const int2* __restrict__ binned, const int* __restrict__ bcnt,
                       const int* __restrict__ boff, const int* __restrict__ srcsBase,
                       int* __restrict__ rs, int* __restrict__ srcs) {
    int b = blockIdx.x;
    int n0 = b * BS;
    if (n0 >= NN) return;
    int nd = NN - n0;
    if (nd > BS) nd = BS;
    int cnt = bcnt[b];
    if (cnt > MAXP) cnt = MAXP;  // statistically impossible; safety
    int base = boff[b];
    int sb = srcsBase[b];
    __shared__ int ldsCnt[256];
    __shared__ int scanA[256];
    __shared__ int rowOffE[256];
    __shared__ int stage[MAXP + BS];
    int tid = threadIdx.x;
    ldsCnt[tid] = 0;
    __syncthreads();
    int srcv[PPT], dl_[PPT], rk_[PPT];
#pragma unroll
    for (int k = 0; k < PPT; ++k) {
        int i = k * 256 + tid;
        if (i < cnt) {
            int2 p = binned[base + i];
            int dl = p.y - n0;
            rk_[k] = atomicAdd(&ldsCnt[dl], 1);
            srcv[k] = p.x;
            dl_[k] = dl;
        } else {
            dl_[k] = -1;
        }
    }
    __syncthreads();
    int v = (tid < nd) ? ldsCnt[tid] + 1 : 0;  // +1 self-loop
    scanA[tid] = v;
    __syncthreads();
    for (int off = 1; off < 256; off <<= 1) {
        int t = (tid >= off) ? scanA[tid - off] : 0;
        __syncthreads();
        scanA[tid] += t;
        __syncthreads();
    }
    rowOffE[tid] = scanA[tid] - v;
    __syncthreads();
    if (tid < nd) {
        int e = rowOffE[tid];
        rs[n0 + tid] = sb + e;
        stage[e] = n0 + tid;  // self-loop occupies first slot
    }
    __syncthreads();
#pragma unroll
    for (int k = 0; k < PPT; ++k)
        if (dl_[k] >= 0) stage[rowOffE[dl_[k]] + 1 + rk_[k]] = srcv[k];
    __syncthreads();
    int tot = cnt + nd;
    for (int i = tid; i < tot; i += 256) srcs[sb + i] = stage[i];
}

// ------ layer 1 gather: lane = (e_i<0..7>, sub<0..7>); 8 edges/iter ---------
// packed-fp32 logit chain (op_sel broadcasts); xr1 precomputed; 5 waves/SIMD.
__global__ __launch_bounds__(256, 5) void k_gat1(
        const float* __restrict__ x, const float* __restrict__ Wl,
        const float* __restrict__ xr1, const float* __restrict__ att,
        const int* __restrict__ rs, const int* __restrict__ srcs,
        const float* __restrict__ b, const float* __restrict__ g,
        const float* __restrict__ be, float* __restrict__ h) {
    int lane = threadIdx.x & 63;
    int wave = (blockIdx.x * blockDim.x + threadIdx.x) >> 6;
    int nwaves = (gridDim.x * blockDim.x) >> 6;
    int e_i = lane >> 3;
    int sub = lane & 7;
    f32x2 wl2[4][4], at2[4];
#pragma unroll
    for (int k = 0; k < 4; ++k)
#pragma unroll
        for (int jp = 0; jp < 4; ++jp)
            wl2[k][jp] = *(const f32x2*)(Wl + k * 64 + sub * 8 + jp * 2);
#pragma unroll
    for (int jp = 0; jp < 4; ++jp)
        at2[jp] = *(const f32x2*)(att + sub * 8 + jp * 2);
    const f32x2 neg2 = {NEG, NEG};

    for (int n = wave; n < NN; n += nwaves) {
        f32x2 xrd2[4];
#pragma unroll
        for (int jp = 0; jp < 4; ++jp)
            xrd2[jp] = *(const f32x2*)(xr1 + (long long)n * 64 + sub * 8 + jp * 2);
        int beg = rs[n];
        int end = rs[n + 1];
        float acc4[4] = {0.f, 0.f, 0.f, 0.f};
        float den = 0.f;
        int slot = beg + e_i;
        bool valid = slot < end;
        int s = srcs[valid ? slot : beg];
        float4 xa = *(const float4*)(x + (long long)s * 4);
        for (int base = beg; base < end; base += 8) {
            int nslot = base + 8 + e_i;
            bool nvalid = nslot < end;
            int ns = srcs[nvalid ? nslot : beg];
            float4 xn = *(const float4*)(x + (long long)ns * 4);
            const f32x2* xp2 = (const f32x2*)&xa;
            f32x2 p2 = {0.f, 0.f};
#pragma unroll
            for (int jp = 0; jp < 4; ++jp) {
                f32x2 t = pk_fma_blo(xp2[0], wl2[0][jp], xrd2[jp]);  // xa.x
                t = pk_fma_bhi(xp2[0], wl2[1][jp], t);               // xa.y
                t = pk_fma_blo(xp2[1], wl2[2][jp], t);               // xa.z
                t = pk_fma_bhi(xp2[1], wl2[3][jp], t);               // xa.w
                f32x2 nm = pk_mul(t, neg2);
                f32x2 u;
                u[0] = fmaxf(t[0], nm[0]);
                u[1] = fmaxf(t[1], nm[1]);
                p2 = pk_fma(u, at2[jp], p2);
            }
            float p = p2[0] + p2[1];
            p = dppadd<0xB1>(p);                 // xor1: pair of subs = one head
            float ex = valid ? __expf(p) : 0.f;
            den += ex;
            acc4[0] += ex * xa.x;
            acc4[1] += ex * xa.y;
            acc4[2] += ex * xa.z;
            acc4[3] += ex * xa.w;
            xa = xn;
            valid = nvalid;
        }
#pragma unroll
        for (int m = 8; m <= 32; m <<= 1) {
#pragma unroll
            for (int k = 0; k < 4; ++k) acc4[k] += __shfl_xor(acc4[k], m);
            den += __shfl_xor(den, m);
        }
        int cf = sub * 8 + e_i;  // bijection over 0..63, same head as den
        float v = (acc4[0] * Wl[cf] + acc4[1] * Wl[64 + cf] +
                   acc4[2] * Wl[128 + cf] + acc4[3] * Wl[192 + cf]) / den + b[cf];
        // single-pass LN: Sum(v) and Sum(v^2) reduced in parallel chains
        float s1 = wsum64(v);
        float s2 = wsum64(v * v);
        float mu = s1 * (1.f / 64.f);
        float var = fmaxf(s2 * (1.f / 64.f) - mu * mu, 0.f);
        float y = (v - mu) * rsqrtf(var + 1e-5f) * g[cf] + be[cf];
        h[(long long)n * 64 + cf] = y > 0.f ? y : expm1f(y);
    }
}

// ---- layer 2 node transform: h[N,64] @ W[64,32]; xl2 packed bf16 -----------
__global__ void k_lin2(const float* __restrict__ h, const float* __restrict__ Wl,
                       const float* __restrict__ Wr, unsigned* __restrict__ xl2p,
                       float* __restrict__ xr2) {
    __shared__ float wl_s[2048];
    __shared__ float wr_s[2048];
    for (int i = threadIdx.x; i < 2048; i += blockDim.x) {
        wl_s[i] = Wl[i];
        wr_s[i] = Wr[i];
    }
    __syncthreads();
    int t = blockIdx.x * blockDim.x + threadIdx.x;
    if (t >= NN * 16) return;
    int n = t >> 4, j2 = t & 15;
    const float* hr = h + (long long)n * 64;
    float al0 = 0.f, al1 = 0.f, ar0 = 0.f, ar1 = 0.f;
#pragma unroll 8
    for (int k = 0; k < 64; ++k) {
        float hv = hr[k];
        al0 += hv * wl_s[k * 32 + j2 * 2];
        al1 += hv * wl_s[k * 32 + j2 * 2 + 1];
        ar0 += hv * wr_s[k * 32 + j2 * 2];
        ar1 += hv * wr_s[k * 32 + j2 * 2 + 1];
    }
    xl2p[(long long)n * 16 + j2] = (f2bf_rn(al1) << 16) | f2bf_rn(al0);
    *(float2*)(xr2 + (long long)n * 32 + j2 * 2) = {ar0, ar1};
}

// ------ layer 2 gather: lane = (e_i<0..7>, cg<0..7>); 8 edges/iter ----------
// gathers 8B (4 bf16 channels) per lane from packed xl2; single-pass LN.
__global__ void k_gat2(const unsigned* __restrict__ xl2p,
                       const float* __restrict__ xr2,
                       const float* __restrict__ att, const int* __restrict__ rs,
                       const int* __restrict__ srcs, const float* __restrict__ b,
                       const float* __restrict__ g, const float* __restrict__ be,
                       float* __restrict__ out) {
    int lane = threadIdx.x & 63;
    int wave = (blockIdx.x * blockDim.x + threadIdx.x) >> 6;
    int nwaves = (gridDim.x * blockDim.x) >> 6;
    int e_i = lane >> 3;
    int cg = lane & 7;
    float at[4];
#pragma unroll
    for (int j = 0; j < 4; ++j) at[j] = att[cg * 4 + j];

    for (int n = wave; n < NN; n += nwaves) {
        const float4 xr4 = *(const float4*)(xr2 + (long long)n * 32 + cg * 4);
        float xrd[4] = {xr4.x, xr4.y, xr4.z, xr4.w};
        int beg = rs[n];
        int end = rs[n + 1];
        float acc[4] = {0.f, 0.f, 0.f, 0.f};
        float den = 0.f;
        int slot = beg + e_i;
        bool valid = slot < end;
        int s = srcs[valid ? slot : beg];
        uint2 xp = *(const uint2*)(xl2p + (long long)s * 16 + cg * 2);
        for (int base = beg; base < end; base += 8) {
            int nslot = base + 8 + e_i;
            bool nvalid = nslot < end;
            int ns = srcs[nvalid ? nslot : beg];
            uint2 xq = *(const uint2*)(xl2p + (long long)ns * 16 + cg * 2);
            float xv0 = __uint_as_float(xp.x << 16);
            float xv1 = __uint_as_float(xp.x & 0xFFFF0000u);
            float xv2 = __uint_as_float(xp.y << 16);
            float xv3 = __uint_as_float(xp.y & 0xFFFF0000u);
            float u0 = xv0 + xrd[0], u1 = xv1 + xrd[1];
            float u2 = xv2 + xrd[2], u3 = xv3 + xrd[3];
            u0 = fmaxf(u0, NEG * u0);
            u1 = fmaxf(u1, NEG * u1);
            u2 = fmaxf(u2, NEG * u2);
            u3 = fmaxf(u3, NEG * u3);
            float p = u0 * at[0] + u1 * at[1] + u2 * at[2] + u3 * at[3];
            p = dppadd<0xB1>(p);                 // xor1
            p = dppadd<0x4E>(p);                 // xor2 -> quad sums
            p = dppadd<0x141>(p);                // cross-quad -> 8-group sum
            float ex = valid ? __expf(p) : 0.f;
            den += ex;
            acc[0] += ex * xv0;
            acc[1] += ex * xv1;
            acc[2] += ex * xv2;
            acc[3] += ex * xv3;
            xp = xq;
            valid = nvalid;
        }
#pragma unroll
        for (int m = 8; m <= 32; m <<= 1) {
#pragma unroll
            for (int j = 0; j < 4; ++j) acc[j] += __shfl_xor(acc[j], m);
            den += __shfl_xor(den, m);
        }
        int e3 = e_i & 3;
        float v = acc[0];
#pragma unroll
        for (int j = 1; j < 4; ++j) v = (e3 == j) ? acc[j] : v;
        int cf = cg * 4 + e3;
        v = v / den + b[cf];
        // single-pass LN (channels duplicated x2 across 64 lanes -> stats OK)
        float s1 = wsum64(v);
        float s2 = wsum64(v * v);
        float mu = s1 * (1.f / 64.f);
        float var = fmaxf(s2 * (1.f / 64.f) - mu * mu, 0.f);
        float y = (v - mu) * rsqrtf(var + 1e-5f) * g[cf] + be[cf];
        if (e_i < 4) out[(long long)n * 32 + cf] = y;
    }
}

extern "C" void kernel_launch(void* const* d_in, const int* in_sizes, int n_in,
                              void* d_out, int out_size, void* d_ws, size_t ws_size,
                              hipStream_t stream) {
    const float* x   = (const float*)d_in[0];
    const int*   ei  = (const int*)d_in[1];
    const float* W1l = (const float*)d_in[2];
    const float* W1r = (const float*)d_in[3];
    const float* a1  = (const float*)d_in[4];
    const float* b1  = (const float*)d_in[5];
    const float* g1  = (const float*)d_in[6];
    const float* be1 = (const float*)d_in[7];
    const float* W2l = (const float*)d_in[8];
    const float* W2r = (const float*)d_in[9];
    const float* a2  = (const float*)d_in[10];
    const float* b2  = (const float*)d_in[11];
    const float* g2  = (const float*)d_in[12];
    const float* be2 = (const float*)d_in[13];
    float* out = (float*)d_out;

    float* ws = (float*)d_ws;
    float* h   = ws;             // N*64 (layer-1 out; written after CSR done)
    float* xr1 = ws + 6400000;   // N*64 (dead after k_gat1)
    unsigned* xl2p = (unsigned*)(ws + 6400000);  // N*16 uints (reuses xr1)
    float* xr2 = ws + 9600000;   // N*32
    int2* binned = (int2*)ws;    // E0 pairs = 12.8 MB, aliases h (CSR phase only)
    int* ib        = (int*)(ws + 12800000);
    int* rs        = ib;              // NN+1 (sentinel)
    int* srcs      = ib + 100001;     // ETOT
    int* bcnt      = ib + 1800100;    // NB
    int* boff      = ib + 1800100 + NB;
    int* srcsBase  = ib + 1800100 + 2 * NB;
    int* cursor    = ib + 1800100 + 3 * NB;

    // ---- CSR build via 2-level counting sort (+ fused xr1 precompute) ----
    hipMemsetAsync(bcnt, 0, NB * sizeof(int), stream);
    k_bhist<<<256, 256, 0, stream>>>(ei, bcnt, x, W1r, xr1);
    k_bscan<<<1, NB, 0, stream>>>(bcnt, boff, srcsBase, cursor, rs);
    k_bin<<<(E0 + CHUNK - 1) / CHUNK, 256, 0, stream>>>(ei, cursor, binned);
    k_bfin<<<NB, 256, 0, stream>>>(binned, bcnt, boff, srcsBase, rs, srcs);

    // ---- layer 1 ----
    k_gat1<<<2048, 256, 0, stream>>>(x, W1l, xr1, a1, rs, srcs, b1, g1, be1, h);
    // ---- layer 2 ----
    k_lin2<<<(NN * 16 + 255) / 256, 256, 0, stream>>>(h, W2l, W2r, xl2p, xr2);
    k_gat2<<<2048, 256, 0, stream>>>(xl2p, xr2, a2, rs, srcs, b2, g2, be2, out);
}

// Round 19
// 218.772 us; speedup vs baseline: 1.0607x; 1.0607x over previous
//
#include <hip/hip_runtime.h>
#include <math.h>

#define NN 100000
#define E0 1600000
#define ETOT (E0 + NN)
#define NEG 0.2f

#define NB 512          // dst buckets
#define BS 196          // nodes per bucket (NB*BS >= NN)
#define CHUNK 4096      // edges per k_bin block
#define PPT 16          // pairs per thread
#define MAXP 4096       // max pairs per bucket (mean 3136, sigma 56)

// ---- DPP cross-lane adds (VALU pipe, no LDS latency) -----------------------
template <int CTRL>
__device__ __forceinline__ float dppadd(float v) {
    int t = __builtin_amdgcn_update_dpp(0, __float_as_int(v), CTRL, 0xf, 0xf, true);
    return v + __int_as_float(t);
}
// full 64-lane sum, every lane gets the result
__device__ __forceinline__ float wsum64(float v) {
    v = dppadd<0xB1>(v);
    v = dppadd<0x4E>(v);
    v = dppadd<0x141>(v);
    v = dppadd<0x140>(v);
    v += __shfl_xor(v, 16);
    v += __shfl_xor(v, 32);
    return v;
}
__device__ __forceinline__ unsigned f2bf_rn(float f) {
    unsigned u = __float_as_uint(f);
    return (u + 0x7FFFu + ((u >> 16) & 1u)) >> 16;
}

// ---- pass A: bucket histogram (LDS-aggregated) -----------------------------
__global__ void k_bhist(const int* __restrict__ ei, int* __restrict__ bcnt) {
    __shared__ int h[NB];
    int tid = threadIdx.x;
    for (int i = tid; i < NB; i += 256) h[i] = 0;
    __syncthreads();
    int stride = gridDim.x * 256;
    for (int e = blockIdx.x * 256 + tid; e < E0; e += stride)
        atomicAdd(&h[ei[E0 + e] / BS], 1);
    __syncthreads();
    for (int i = tid; i < NB; i += 256)
        if (h[i]) atomicAdd(&bcnt[i], h[i]);
}

// ---- pass B: scan bucket counts --------------------------------------------
__global__ void k_bscan(const int* __restrict__ bcnt, int* __restrict__ boff,
                        int* __restrict__ srcsBase, int* __restrict__ cursor,
                        int* __restrict__ rs) {
    __shared__ int s[NB];
    int tid = threadIdx.x;
    int v = bcnt[tid];
    s[tid] = v;
    __syncthreads();
    for (int off = 1; off < NB; off <<= 1) {
        int t = (tid >= off) ? s[tid - off] : 0;
        __syncthreads();
        s[tid] += t;
        __syncthreads();
    }
    int excl = s[tid] - v;
    boff[tid] = excl;
    cursor[tid] = excl;
    int n0 = tid * BS;
    if (n0 > NN) n0 = NN;
    srcsBase[tid] = excl + n0;  // + self-loops of all earlier nodes
    if (tid == 0) rs[NN] = ETOT;  // sentinel
}

// ---- pass C: bin edges into bucket-sorted pair array (run-aggregated) ------
__global__ void k_bin(const int* __restrict__ ei, int* __restrict__ cursor,
                      int2* __restrict__ binned) {
    __shared__ int hist[NB];
    __shared__ int basesh[NB];
    int tid = threadIdx.x;
    long long cbase = (long long)blockIdx.x * CHUNK;
    for (int i = tid; i < NB; i += 256) hist[i] = 0;
    __syncthreads();
    int srcv[PPT], dstv[PPT], rank[PPT], bkt[PPT];
#pragma unroll
    for (int k = 0; k < PPT; ++k) {
        long long e = cbase + k * 256 + tid;
        if (e < E0) {
            int s_ = ei[e];
            int d_ = ei[E0 + e];
            int b = d_ / BS;
            rank[k] = atomicAdd(&hist[b], 1);
            srcv[k] = s_;
            dstv[k] = d_;
            bkt[k] = b;
        } else {
            bkt[k] = -1;
        }
    }
    __syncthreads();
    for (int i = tid; i < NB; i += 256)
        if (hist[i] > 0) basesh[i] = atomicAdd(&cursor[i], hist[i]);
    __syncthreads();
#pragma unroll
    for (int k = 0; k < PPT; ++k)
        if (bkt[k] >= 0) {
            int2 p;
            p.x = srcv[k];
            p.y = dstv[k];
            binned[basesh[bkt[k]] + rank[k]] = p;
        }
}

// ---- pass D: per-bucket finalize: row_start + dst-sorted srcs (coalesced) --
__global__ void k_bfin(const int2* __restrict__ binned, const int* __restrict__ bcnt,
                       const int* __restrict__ boff, const int* __restrict__ srcsBase,
                       int* __restrict__ rs, int* __restrict__ srcs) {
    int b = blockIdx.x;
    int n0 = b * BS;
    if (n0 >= NN) return;
    int nd = NN - n0;
    if (nd > BS) nd = BS;
    int cnt = bcnt[b];
    if (cnt > MAXP) cnt = MAXP;  // statistically impossible; safety
    int base = boff[b];
    int sb = srcsBase[b];
    __shared__ int ldsCnt[256];
    __shared__ int scanA[256];
    __shared__ int rowOffE[256];
    __shared__ int stage[MAXP + BS];
    int tid = threadIdx.x;
    ldsCnt[tid] = 0;
    __syncthreads();
    int srcv[PPT], dl_[PPT], rk_[PPT];
#pragma unroll
    for (int k = 0; k < PPT; ++k) {
        int i = k * 256 + tid;
        if (i < cnt) {
            int2 p = binned[base + i];
            int dl = p.y - n0;
            rk_[k] = atomicAdd(&ldsCnt[dl], 1);
            srcv[k] = p.x;
            dl_[k] = dl;
        } else {
            dl_[k] = -1;
        }
    }
    __syncthreads();
    int v = (tid < nd) ? ldsCnt[tid] + 1 : 0;  // +1 self-loop
    scanA[tid] = v;
    __syncthreads();
    for (int off = 1; off < 256; off <<= 1) {
        int t = (tid >= off) ? scanA[tid - off] : 0;
        __syncthreads();
        scanA[tid] += t;
        __syncthreads();
    }
    rowOffE[tid] = scanA[tid] - v;
    __syncthreads();
    if (tid < nd) {
        int e = rowOffE[tid];
        rs[n0 + tid] = sb + e;
        stage[e] = n0 + tid;  // self-loop occupies first slot
    }
    __syncthreads();
#pragma unroll
    for (int k = 0; k < PPT; ++k)
        if (dl_[k] >= 0) stage[rowOffE[dl_[k]] + 1 + rk_[k]] = srcv[k];
    __syncthreads();
    int tot = cnt + nd;
    for (int i = tid; i < tot; i += 256) srcs[sb + i] = stage[i];
}

// ------ layer 1 gather: lane = (e_i<0..7>, sub<0..7>); 8 edges/iter ---------
// Wl/Wr columns register-resident; DPP for head-pair reduce + LN. (R13 best)
__global__ void k_gat1(const float* __restrict__ x, const float* __restrict__ Wl,
                       const float* __restrict__ Wr, const float* __restrict__ att,
                       const int* __restrict__ rs, const int* __restrict__ srcs,
                       const float* __restrict__ b, const float* __restrict__ g,
                       const float* __restrict__ be, float* __restrict__ h) {
    int lane = threadIdx.x & 63;
    int wave = (blockIdx.x * blockDim.x + threadIdx.x) >> 6;
    int nwaves = (gridDim.x * blockDim.x) >> 6;
    int e_i = lane >> 3;
    int sub = lane & 7;
    float wl[4][8], wr[4][8], at[8];
#pragma unroll
    for (int k = 0; k < 4; ++k)
#pragma unroll
        for (int j = 0; j < 8; ++j) {
            wl[k][j] = Wl[k * 64 + sub * 8 + j];
            wr[k][j] = Wr[k * 64 + sub * 8 + j];
        }
#pragma unroll
    for (int j = 0; j < 8; ++j) at[j] = att[sub * 8 + j];

    for (int n = wave; n < NN; n += nwaves) {
        const float4 xd = *(const float4*)(x + (long long)n * 4);
        float xrd[8];
#pragma unroll
        for (int j = 0; j < 8; ++j)
            xrd[j] = xd.x * wr[0][j] + xd.y * wr[1][j] + xd.z * wr[2][j] +
                     xd.w * wr[3][j];
        int beg = rs[n];
        int end = rs[n + 1];
        float acc4[4] = {0.f, 0.f, 0.f, 0.f};
        float den = 0.f;
        int slot = beg + e_i;
        bool valid = slot < end;
        int s = srcs[valid ? slot : beg];
        float4 xa = *(const float4*)(x + (long long)s * 4);
        for (int base = beg; base < end; base += 8) {
            int nslot = base + 8 + e_i;
            bool nvalid = nslot < end;
            int ns = srcs[nvalid ? nslot : beg];
            float4 xn = *(const float4*)(x + (long long)ns * 4);
            float p = 0.f;
#pragma unroll
            for (int j = 0; j < 8; ++j) {
                float t = xa.x * wl[0][j] + xa.y * wl[1][j] + xa.z * wl[2][j] +
                          xa.w * wl[3][j];
                float u = t + xrd[j];
                u = fmaxf(u, NEG * u);
                p += u * at[j];
            }
            p = dppadd<0xB1>(p);                 // xor1: pair of subs = one head
            float ex = valid ? __expf(p) : 0.f;
            den += ex;
            acc4[0] += ex * xa.x;
            acc4[1] += ex * xa.y;
            acc4[2] += ex * xa.z;
            acc4[3] += ex * xa.w;
            xa = xn;
            valid = nvalid;
        }
#pragma unroll
        for (int m = 8; m <= 32; m <<= 1) {
#pragma unroll
            for (int k = 0; k < 4; ++k) acc4[k] += __shfl_xor(acc4[k], m);
            den += __shfl_xor(den, m);
        }
        int cf = sub * 8 + e_i;  // bijection over 0..63, same head as den
        float v = (acc4[0] * Wl[cf] + acc4[1] * Wl[64 + cf] +
                   acc4[2] * Wl[128 + cf] + acc4[3] * Wl[192 + cf]) / den + b[cf];
        float mu = wsum64(v) * (1.f / 64.f);
        float c = v - mu;
        float var = wsum64(c * c) * (1.f / 64.f);
        float y = c * rsqrtf(var + 1e-5f) * g[cf] + be[cf];
        h[(long long)n * 64 + cf] = y > 0.f ? y : expm1f(y);
    }
}

// ---- layer 2 node transform: h[N,64] @ W[64,32]; xl2 packed bf16 -----------
// thread computes 2 adjacent channels; xl2p[n*16+j2] = bf16(c1)<<16 | bf16(c0)
__global__ void k_lin2(const float* __restrict__ h, const float* __restrict__ Wl,
                       const float* __restrict__ Wr, unsigned* __restrict__ xl2p,
                       float* __restrict__ xr2) {
    __shared__ float wl_s[2048];
    __shared__ float wr_s[2048];
    for (int i = threadIdx.x; i < 2048; i += blockDim.x) {
        wl_s[i] = Wl[i];
        wr_s[i] = Wr[i];
    }
    __syncthreads();
    int t = blockIdx.x * blockDim.x + threadIdx.x;
    if (t >= NN * 16) return;
    int n = t >> 4, j2 = t & 15;
    const float* hr = h + (long long)n * 64;
    float al0 = 0.f, al1 = 0.f, ar0 = 0.f, ar1 = 0.f;
#pragma unroll 8
    for (int k = 0; k < 64; ++k) {
        float hv = hr[k];
        al0 += hv * wl_s[k * 32 + j2 * 2];
        al1 += hv * wl_s[k * 32 + j2 * 2 + 1];
        ar0 += hv * wr_s[k * 32 + j2 * 2];
        ar1 += hv * wr_s[k * 32 + j2 * 2 + 1];
    }
    xl2p[(long long)n * 16 + j2] = (f2bf_rn(al1) << 16) | f2bf_rn(al0);
    *(float2*)(xr2 + (long long)n * 32 + j2 * 2) = {ar0, ar1};
}

// ------ layer 2 gather: lane = (e_i<0..7>, cg<0..7>); 8 edges/iter ----------
// gathers 8B (4 bf16 channels) per lane from packed xl2.
__global__ void k_gat2(const unsigned* __restrict__ xl2p,
                       const float* __restrict__ xr2,
                       const float* __restrict__ att, const int* __restrict__ rs,
                       const int* __restrict__ srcs, const float* __restrict__ b,
                       const float* __restrict__ g, const float* __restrict__ be,
                       float* __restrict__ out) {
    int lane = threadIdx.x & 63;
    int wave = (blockIdx.x * blockDim.x + threadIdx.x) >> 6;
    int nwaves = (gridDim.x * blockDim.x) >> 6;
    int e_i = lane >> 3;
    int cg = lane & 7;
    float at[4];
#pragma unroll
    for (int j = 0; j < 4; ++j) at[j] = att[cg * 4 + j];

    for (int n = wave; n < NN; n += nwaves) {
        const float4 xr4 = *(const float4*)(xr2 + (long long)n * 32 + cg * 4);
        float xrd[4] = {xr4.x, xr4.y, xr4.z, xr4.w};
        int beg = rs[n];
        int end = rs[n + 1];
        float acc[4] = {0.f, 0.f, 0.f, 0.f};
        float den = 0.f;
        int slot = beg + e_i;
        bool valid = slot < end;
        int s = srcs[valid ? slot : beg];
        uint2 xp = *(const uint2*)(xl2p + (long long)s * 16 + cg * 2);
        for (int base = beg; base < end; base += 8) {
            int nslot = base + 8 + e_i;
            bool nvalid = nslot < end;
            int ns = srcs[nvalid ? nslot : beg];
            uint2 xq = *(const uint2*)(xl2p + (long long)ns * 16 + cg * 2);
            float xv0 = __uint_as_float(xp.x << 16);
            float xv1 = __uint_as_float(xp.x & 0xFFFF0000u);
            float xv2 = __uint_as_float(xp.y << 16);
            float xv3 = __uint_as_float(xp.y & 0xFFFF0000u);
            float u0 = xv0 + xrd[0], u1 = xv1 + xrd[1];
            float u2 = xv2 + xrd[2], u3 = xv3 + xrd[3];
            u0 = fmaxf(u0, NEG * u0);
            u1 = fmaxf(u1, NEG * u1);
            u2 = fmaxf(u2, NEG * u2);
            u3 = fmaxf(u3, NEG * u3);
            float p = u0 * at[0] + u1 * at[1] + u2 * at[2] + u3 * at[3];
            p = dppadd<0xB1>(p);                 // xor1
            p = dppadd<0x4E>(p);                 // xor2 -> quad sums
            p = dppadd<0x141>(p);                // cross-quad -> 8-group sum
            float ex = valid ? __expf(p) : 0.f;
            den += ex;
            acc[0] += ex * xv0;
            acc[1] += ex * xv1;
            acc[2] += ex * xv2;
            acc[3] += ex * xv3;
            xp = xq;
            valid = nvalid;
        }
#pragma unroll
        for (int m = 8; m <= 32; m <<= 1) {
#pragma unroll
            for (int j = 0; j < 4; ++j) acc[j] += __shfl_xor(acc[j], m);
            den += __shfl_xor(den, m);
        }
        int e3 = e_i & 3;
        float v = acc[0];
#pragma unroll
        for (int j = 1; j < 4; ++j) v = (e3 == j) ? acc[j] : v;
        int cf = cg * 4 + e3;
        v = v / den + b[cf];
        float mu = wsum64(v) * (1.f / 64.f);
        float cc = v - mu;
        float var = wsum64(cc * cc) * (1.f / 64.f);
        float y = cc * rsqrtf(var + 1e-5f) * g[cf] + be[cf];
        if (e_i < 4) out[(long long)n * 32 + cf] = y;
    }
}

extern "C" void kernel_launch(void* const* d_in, const int* in_sizes, int n_in,
                              void* d_out, int out_size, void* d_ws, size_t ws_size,
                              hipStream_t stream) {
    const float* x   = (const float*)d_in[0];
    const int*   ei  = (const int*)d_in[1];
    const float* W1l = (const float*)d_in[2];
    const float* W1r = (const float*)d_in[3];
    const float* a1  = (const float*)d_in[4];
    const float* b1  = (const float*)d_in[5];
    const float* g1  = (const float*)d_in[6];
    const float* be1 = (const float*)d_in[7];
    const float* W2l = (const float*)d_in[8];
    const float* W2r = (const float*)d_in[9];
    const float* a2  = (const float*)d_in[10];
    const float* b2  = (const float*)d_in[11];
    const float* g2  = (const float*)d_in[12];
    const float* be2 = (const float*)d_in[13];
    float* out = (float*)d_out;

    float* ws = (float*)d_ws;
    float* h   = ws;             // N*64 (layer-1 out; written after CSR done)
    unsigned* xl2p = (unsigned*)(ws + 6400000);  // N*16 uints (packed bf16 x2)
    float* xr2 = ws + 9600000;   // N*32
    int2* binned = (int2*)ws;    // E0 pairs = 12.8 MB, aliases h (CSR phase only)
    int* ib        = (int*)(ws + 12800000);
    int* rs        = ib;              // NN+1 (sentinel)
    int* srcs      = ib + 100001;     // ETOT
    int* bcnt      = ib + 1800100;    // NB
    int* boff      = ib + 1800100 + NB;
    int* srcsBase  = ib + 1800100 + 2 * NB;
    int* cursor    = ib + 1800100 + 3 * NB;

    // ---- CSR build via 2-level counting sort ----
    hipMemsetAsync(bcnt, 0, NB * sizeof(int), stream);
    k_bhist<<<256, 256, 0, stream>>>(ei, bcnt);
    k_bscan<<<1, NB, 0, stream>>>(bcnt, boff, srcsBase, cursor, rs);
    k_bin<<<(E0 + CHUNK - 1) / CHUNK, 256, 0, stream>>>(ei, cursor, binned);
    k_bfin<<<NB, 256, 0, stream>>>(binned, bcnt, boff, srcsBase, rs, srcs);

    // ---- layer 1 (xl/xr recomputed from x in-wave) ----
    k_gat1<<<2048, 256, 0, stream>>>(x, W1l, W1r, a1, rs, srcs, b1, g1, be1, h);
    // ---- layer 2 ----
    k_lin2<<<(NN * 16 + 255) / 256, 256, 0, stream>>>(h, W2l, W2r, xl2p, xr2);
    k_gat2<<<2048, 256, 0, stream>>>(xl2p, xr2, a2, rs, srcs, b2, g2, be2, out);
}